// Round 8
// baseline (340.467 us; speedup 1.0000x reference)
//
#include <hip/hip_runtime.h>
#include <math.h>

#define N 4096
#define E 32
#define NBLK 12
#define D_IN 2240
#define H1 256
#define H2 32
#define NOUT 51
#define MT 16
#define NPAD (N + E*(MT-1))   // 4576
#define NTILE (NPAD/MT)       // 286
#define KSPLIT 4
#define NROWS 4608
#define GMAX 96
#define NCONVBLK (35*4*E)     // 4480

typedef short s8v __attribute__((ext_vector_type(8)));
typedef float f4v __attribute__((ext_vector_type(4)));

__device__ __forceinline__ float gelu(float x){
    return 0.5f * x * (1.0f + erff(x * 0.70710678118654752f));
}
__device__ __forceinline__ unsigned short f2bf(float f){
    unsigned int u = __float_as_uint(f);
    unsigned int r = (u + 0x7fffu + ((u >> 16) & 1u)) >> 16;
    return (unsigned short)r;
}
__device__ __forceinline__ float bflo(unsigned int u){ return __uint_as_float(u << 16); }
__device__ __forceinline__ float bfhi(unsigned int u){ return __uint_as_float(u & 0xffff0000u); }

// ---------------- sort rows by expert + build 8-tile groups ----------------
__global__ void k_sort(const int* __restrict__ desc,
                       int* __restrict__ perm, int* __restrict__ tile_e,
                       int4* __restrict__ garr, int* __restrict__ ngroups){
    __shared__ int scnt[E];
    __shared__ int spoff[E+1];
    __shared__ int scur[E];
    int tid = threadIdx.x;
    if (tid < E) scnt[tid] = 0;
    __syncthreads();
    for (int n = tid; n < N; n += blockDim.x) atomicAdd(&scnt[desc[n]], 1);
    __syncthreads();
    if (tid == 0){
        int run = 0;
        for (int e = 0; e < E; e++){ spoff[e] = run; run += ((scnt[e] + MT - 1)/MT)*MT; }
        spoff[E] = run;
        int ng = 0;
        for (int e = 0; e < E; e++){
            int t0 = spoff[e]/MT, t1 = spoff[e+1]/MT;
            for (int t = t0; t < t1; t += 8){
                int nv = t1 - t; if (nv > 8) nv = 8;
                if (ng < GMAX) garr[ng] = make_int4(t, e, nv, 0);
                ng++;
            }
        }
        *ngroups = (ng > GMAX) ? GMAX : ng;
    }
    __syncthreads();
    if (tid < E) scur[tid] = spoff[tid];
    for (int p = tid; p < NPAD; p += blockDim.x) perm[p] = -1;
    __syncthreads();
    for (int n = tid; n < N; n += blockDim.x){
        int p = atomicAdd(&scur[desc[n]], 1);
        perm[p] = n;
    }
    for (int t = tid; t < NTILE; t += blockDim.x){
        int p0 = t*MT;
        int e = -1;
        if (p0 < spoff[E]){
            for (int q = 0; q < E; q++){
                if (p0 >= spoff[q] && p0 < spoff[q+1]){ e = q; break; }
            }
        }
        tile_e[t] = e;
    }
}

// -------- merged: build feature vectors (blocks 0..NPAD-1) + convert fc1_w (rest) --------
__global__ void k_prep(const int* __restrict__ perm,
                       const int* __restrict__ piece_idx,
                       const int* __restrict__ side_flag,
                       const int* __restrict__ ep_file,
                       const float* __restrict__ castle_ms,
                       const float* __restrict__ fifty_a,
                       const int* __restrict__ desc_idx,
                       const float* __restrict__ Wp_w, const float* __restrict__ Wp_b,
                       const float* __restrict__ Wc_w, const float* __restrict__ Wc_b,
                       const float* __restrict__ Wep_w, const float* __restrict__ Wep_b,
                       const float* __restrict__ Wf_w, const float* __restrict__ Wf_b,
                       unsigned short* __restrict__ xs,
                       const float* __restrict__ W1, unsigned short* __restrict__ Wt){
    __shared__ float lds[64][65];
    int tid = threadIdx.x;
    if (blockIdx.x >= NPAD){
        int b = blockIdx.x - NPAD;
        int kt = b % 35;
        int nt = (b / 35) & 3;
        int e  = b / 140;
        int k0 = kt*64, n0 = nt*64;
        int kk = tid >> 4, nn = (tid & 15) * 4;
        const float* src = W1 + ((size_t)e*D_IN + k0)*H1 + n0;
        #pragma unroll
        for (int r = 0; r < 4; r++){
            float4 v = *(const float4*)(src + (size_t)(kk + r*16)*H1 + nn);
            lds[kk + r*16][nn]   = v.x;
            lds[kk + r*16][nn+1] = v.y;
            lds[kk + r*16][nn+2] = v.z;
            lds[kk + r*16][nn+3] = v.w;
        }
        __syncthreads();
        int n = tid >> 2, kq = tid & 3;
        s8v p0, p1;
        #pragma unroll
        for (int j = 0; j < 8; j++) p0[j] = (short)f2bf(lds[kq*16 + j][n]);
        #pragma unroll
        for (int j = 0; j < 8; j++) p1[j] = (short)f2bf(lds[kq*16 + 8 + j][n]);
        unsigned short* dst = Wt + ((size_t)(e*H1 + n0 + n))*D_IN + k0 + kq*16;
        *(s8v*)dst       = p0;
        *(s8v*)(dst + 8) = p1;
        return;
    }
    int pos = blockIdx.x;
    int row = perm[pos];
    unsigned short* xr = xs + (size_t)pos * D_IN;
    if (row < 0){
        s8v z = {0,0,0,0,0,0,0,0};
        for (int t = tid; t < D_IN/8; t += blockDim.x) *(s8v*)(xr + t*8) = z;
        return;
    }
    int d = desc_idx[row];
    int s = side_flag[row];
    __shared__ int pidx[64];
    if (tid < 64) pidx[tid] = piece_idx[row*64 + tid];
    __syncthreads();
    const float* Wp  = s ? Wp_b  : Wp_w;
    const float* Wc  = s ? Wc_b  : Wc_w;
    const float* Wep = s ? Wep_b : Wep_w;
    const float* Wf  = s ? Wf_b  : Wf_w;
    int ep  = ep_file[row];
    int epc = ep > 0 ? ep : 0;
    float a = fifty_a[row];
    for (int t = tid; t < D_IN/8; t += blockDim.x){
        int i0 = t*8;
        float v[8];
        if (i0 < 2048){
            int sq = i0 >> 5, c0 = i0 & 31;
            int pc = pidx[sq];
            float msk = pc >= 0 ? 1.0f : 0.0f;
            int pcc = pc > 0 ? pc : 0;
            const float* base = Wp + (((size_t)d*64 + sq)*12 + pcc)*32 + c0;
            float4 a0 = *(const float4*)base;
            float4 a1 = *(const float4*)(base + 4);
            v[0]=a0.x*msk; v[1]=a0.y*msk; v[2]=a0.z*msk; v[3]=a0.w*msk;
            v[4]=a1.x*msk; v[5]=a1.y*msk; v[6]=a1.z*msk; v[7]=a1.w*msk;
        } else if (i0 < 2176){
            int j = i0 - 2048; int ci = j >> 5, c0 = j & 31;
            float cv = castle_ms[row*4 + ci];
            const float* base = Wc + ((size_t)d*4 + ci)*32 + c0;
            float4 a0 = *(const float4*)base;
            float4 a1 = *(const float4*)(base + 4);
            v[0]=a0.x*cv; v[1]=a0.y*cv; v[2]=a0.z*cv; v[3]=a0.w*cv;
            v[4]=a1.x*cv; v[5]=a1.y*cv; v[6]=a1.z*cv; v[7]=a1.w*cv;
        } else if (i0 < 2208){
            int c0 = i0 - 2176;
            float msk = ep >= 0 ? 1.0f : 0.0f;
            const float* base = Wep + ((size_t)d*8 + epc)*32 + c0;
            float4 a0 = *(const float4*)base;
            float4 a1 = *(const float4*)(base + 4);
            v[0]=a0.x*msk; v[1]=a0.y*msk; v[2]=a0.z*msk; v[3]=a0.w*msk;
            v[4]=a1.x*msk; v[5]=a1.y*msk; v[6]=a1.z*msk; v[7]=a1.w*msk;
        } else {
            int c0 = i0 - 2208;
            #pragma unroll
            for (int j = 0; j < 8; j++)
                v[j] = (1.0f - a) * Wf[(size_t)d*64 + c0 + j] + a * Wf[(size_t)d*64 + 32 + c0 + j];
        }
        s8v p;
        #pragma unroll
        for (int j = 0; j < 8; j++) p[j] = (short)f2bf(v[j]);
        *(s8v*)(xr + i0) = p;
    }
}

// ------- fc1 MFMA: groups of 128 rows x 256 cols, K split 4, partial f32 out -------
__launch_bounds__(256)
__global__ void k_fc1(const int4* __restrict__ garr, const int* __restrict__ ngroups,
                      const unsigned short* __restrict__ xs,
                      const unsigned short* __restrict__ Wt,
                      float* __restrict__ h1p){
    int g = blockIdx.x;
    if (g >= *ngroups) return;
    int4 gi = garr[g];
    int tile0 = gi.x, e = gi.y, nv = gi.z;
    int kc = blockIdx.y, nh = blockIdx.z;
    int kstart = (kc <= 2) ? kc*18 : 53;
    int nsteps = (kc < 2) ? 18 : 17;
    int lane = threadIdx.x & 63, wave = threadIdx.x >> 6;
    int quad = lane >> 4, l16 = lane & 15;
    int col0 = nh*128 + wave*32 + l16;
    const unsigned short* Ab = xs + (size_t)(tile0*MT + l16)*D_IN + quad*8;
    const unsigned short* B0 = Wt + ((size_t)e*H1 + col0)*D_IN + quad*8;
    const unsigned short* B1 = B0 + (size_t)16*D_IN;
    f4v acc[8][2];
    #pragma unroll
    for (int mt = 0; mt < 8; mt++){ acc[mt][0] = (f4v){0.f,0.f,0.f,0.f}; acc[mt][1] = (f4v){0.f,0.f,0.f,0.f}; }
    int kend = kstart + nsteps;
    #pragma unroll 2
    for (int s = kstart; s < kend; s++){
        int ko = s*32;
        s8v b0 = *(const s8v*)(B0 + ko);
        s8v b1 = *(const s8v*)(B1 + ko);
        #pragma unroll
        for (int mt = 0; mt < 8; mt++){
            s8v av = *(const s8v*)(Ab + (size_t)mt*MT*D_IN + ko);
            acc[mt][0] = __builtin_amdgcn_mfma_f32_16x16x32_bf16(av, b0, acc[mt][0], 0, 0, 0);
            acc[mt][1] = __builtin_amdgcn_mfma_f32_16x16x32_bf16(av, b1, acc[mt][1], 0, 0, 0);
        }
    }
    float* out = h1p + (size_t)kc*NROWS*H1;
    #pragma unroll
    for (int mt = 0; mt < 8; mt++){
        if (mt >= nv) break;
        int posb = (tile0 + mt)*MT + quad*4;
        #pragma unroll
        for (int r = 0; r < 4; r++){
            out[(size_t)(posb + r)*H1 + col0]      = acc[mt][0][r];
            out[(size_t)(posb + r)*H1 + col0 + 16] = acc[mt][1][r];
        }
    }
}

// ------- fused tail: fc2(+LN1,LN2) + 12 residual blocks + out-proj/softmax -------
// 1024 threads = 16 waves; wave w owns row (t*MT + w); 2-way k-split per GEMV.
// All weights staged ONCE (bf16 k-pair packed); residual loop has ZERO barriers.
__launch_bounds__(1024)
__global__ void k_tail(const int* __restrict__ tile_e, const int* __restrict__ perm,
                       const float* __restrict__ h1p, const float* __restrict__ b1,
                       const float* __restrict__ g1, const float* __restrict__ be1,
                       const float* __restrict__ W2, const float* __restrict__ b2,
                       const float* __restrict__ g2, const float* __restrict__ be2,
                       const float* __restrict__ Aw, const float* __restrict__ Abv,
                       const float* __restrict__ Ag, const float* __restrict__ Abe,
                       const float* __restrict__ Bw, const float* __restrict__ Bb,
                       const float* __restrict__ Bg, const float* __restrict__ Bbe,
                       const float* __restrict__ Ow, const float* __restrict__ Ob,
                       const float* __restrict__ bins,
                       float* __restrict__ out){
    int t = blockIdx.x;
    int e = tile_e[t];
    if (e < 0) return;
    int tid = threadIdx.x;
    int wave = tid >> 6, lane = tid & 63;
    int c = lane & 31, kk = lane >> 5;
    int m = wave;

    __shared__ __align__(16) unsigned int smem[12288];   // 48 KB union
    __shared__ __align__(16) float vecs[NBLK*6*32];      // 9 KB
    __shared__ __align__(16) float sh2[MT][36];
    __shared__ __align__(16) float sh3[MT][36];

    float* shf = (float*)smem;                 // [16][260] floats, phase 1
    unsigned int* W2pk = smem + 4160;          // 4096 u32, phase 1

    // ---- phase 1a: W2 -> bf16 k-pair packed ----
    {
        const float* W2e = W2 + (size_t)e*H1*H2;
        for (int j = tid; j < 4096; j += 1024){
            int h = j & 1, q = j >> 1, cc = q & 31, p2 = q >> 5;
            int k0 = 4*p2 + 2*h;
            unsigned int lo = f2bf(W2e[k0*32 + cc]);
            unsigned int hi = f2bf(W2e[(k0+1)*32 + cc]);
            W2pk[(p2*32 + cc)*2 + h] = lo | (hi << 16);
        }
    }
    // ---- phase 1b: LN/bias vectors for all 12 blocks ----
    for (int j = tid; j < NBLK*6*32; j += 1024){
        int cc = j & 31, vi = (j >> 5) % 6, tb = j / 192;
        size_t wb = (size_t)tb*E + e;
        const float* src;
        switch(vi){ case 0: src=Abv; break; case 1: src=Ag; break; case 2: src=Abe; break;
                    case 3: src=Bb;  break; case 4: src=Bg; break; default: src=Bbe; }
        vecs[j] = src[wb*32 + cc];
    }
    // ---- phase 1c: sum fc1 K-partials + bias + gelu -> shf (1 float4 per thread) ----
    {
        int r = tid >> 6, c4 = (tid & 63) << 2;
        int row = t*MT + r;
        float4 v = {0.f,0.f,0.f,0.f};
        #pragma unroll
        for (int kc = 0; kc < KSPLIT; kc++){
            float4 p = *(const float4*)(h1p + ((size_t)kc*NROWS + row)*H1 + c4);
            v.x += p.x; v.y += p.y; v.z += p.z; v.w += p.w;
        }
        float4 bb = *(const float4*)(b1 + e*H1 + c4);
        float4 g4;
        g4.x = gelu(v.x + bb.x); g4.y = gelu(v.y + bb.y);
        g4.z = gelu(v.z + bb.z); g4.w = gelu(v.w + bb.w);
        *(float4*)(shf + r*260 + c4) = g4;
    }
    __syncthreads();

    // ---- LN1 (wave-local on row m, 4 elems/lane) ----
    {
        float4 h4 = *(const float4*)(shf + m*260 + lane*4);
        float s = (h4.x + h4.y) + (h4.z + h4.w);
        #pragma unroll
        for (int o = 32; o > 0; o >>= 1) s += __shfl_xor(s, o);
        float mean = s * (1.0f/H1);
        float d0 = h4.x-mean, d1 = h4.y-mean, d2 = h4.z-mean, d3 = h4.w-mean;
        float v2 = (d0*d0 + d1*d1) + (d2*d2 + d3*d3);
        #pragma unroll
        for (int o = 32; o > 0; o >>= 1) v2 += __shfl_xor(v2, o);
        float rs = rsqrtf(v2 * (1.0f/H1) + 1e-5f);
        float4 gg = *(const float4*)(g1 + e*H1 + lane*4);
        float4 gb = *(const float4*)(be1 + e*H1 + lane*4);
        float4 hn;
        hn.x = d0*rs*gg.x + gb.x; hn.y = d1*rs*gg.y + gb.y;
        hn.z = d2*rs*gg.z + gb.z; hn.w = d3*rs*gg.w + gb.w;
        *(float4*)(shf + m*260 + lane*4) = hn;
    }
    // ---- fc2 GEMV [256->32], k-split across kk halves ----
    float hv;
    {
        const uint2* W2p = (const uint2*)W2pk;
        float q0=0.f,q1=0.f,q2=0.f,q3=0.f;
        #pragma unroll 8
        for (int j = 0; j < 32; j++){
            int p2 = kk*32 + j;
            uint2 w = W2p[p2*32 + c];
            float4 h4 = *(const float4*)(shf + m*260 + p2*4);
            q0 = fmaf(h4.x, bflo(w.x), q0);
            q1 = fmaf(h4.y, bfhi(w.x), q1);
            q2 = fmaf(h4.z, bflo(w.y), q2);
            q3 = fmaf(h4.w, bfhi(w.y), q3);
        }
        float acc = (q0+q1) + (q2+q3);
        acc += __shfl_xor(acc, 32);
        acc += b2[e*H2 + c];
        float y = gelu(acc);
        float ss = y;
        #pragma unroll
        for (int o = 16; o > 0; o >>= 1) ss += __shfl_xor(ss, o);
        float mean2 = ss * (1.0f/H2);
        float dv = y - mean2;
        float vv = dv*dv;
        #pragma unroll
        for (int o = 16; o > 0; o >>= 1) vv += __shfl_xor(vv, o);
        hv = dv * rsqrtf(vv*(1.0f/H2) + 1e-5f) * g2[e*H2+c] + be2[e*H2+c];
    }
    __syncthreads();   // done with shf/W2pk

    // ---- phase 2: stage all 12x2 residual weight matrices, bf16 k-pair packed ----
    for (int j = tid; j < 12288; j += 1024){
        int tbsub = j >> 9, r = j & 511;
        int h = r & 1, q = r >> 1, cc = q & 31;
        int p2 = q >> 5;
        int k0 = 4*p2 + 2*h;
        const float* src = (tbsub & 1) ? Bw : Aw;
        size_t base = ((size_t)(tbsub >> 1)*E + e)*1024;
        unsigned int lo = f2bf(src[base + k0*32 + cc]);
        unsigned int hi = f2bf(src[base + (k0+1)*32 + cc]);
        smem[j] = lo | (hi << 16);
    }
    __syncthreads();

    // ---- 12 residual blocks: zero barriers, wave-synchronous, 2-way k-split ----
    for (int tb = 0; tb < NBLK; tb++){
        const float* vA = &vecs[tb*192];
        const uint2* WA = (const uint2*)(smem + (tb*2+0)*512);
        const uint2* WB = (const uint2*)(smem + (tb*2+1)*512);
        sh2[m][c] = hv;
        float q0=0.f,q1=0.f,q2=0.f,q3=0.f;
        #pragma unroll
        for (int j = 0; j < 4; j++){
            int p2 = kk*4 + j;
            uint2 w = WA[p2*32 + c];
            float4 h4 = *(const float4*)(&sh2[m][p2*4]);
            q0 = fmaf(h4.x, bflo(w.x), q0);
            q1 = fmaf(h4.y, bfhi(w.x), q1);
            q2 = fmaf(h4.z, bflo(w.y), q2);
            q3 = fmaf(h4.w, bfhi(w.y), q3);
        }
        float ya = (q0+q1) + (q2+q3);
        ya += __shfl_xor(ya, 32);
        ya += vA[c];
        ya = gelu(ya);
        float sa = ya;
        #pragma unroll
        for (int o = 16; o > 0; o >>= 1) sa += __shfl_xor(sa, o);
        float ma = sa * (1.0f/H2);
        float da = ya - ma;
        float va = da*da;
        #pragma unroll
        for (int o = 16; o > 0; o >>= 1) va += __shfl_xor(va, o);
        float yA = da * rsqrtf(va*(1.0f/H2) + 1e-5f) * vA[32+c] + vA[64+c];
        sh3[m][c] = yA;
        q0=0.f; q1=0.f; q2=0.f; q3=0.f;
        #pragma unroll
        for (int j = 0; j < 4; j++){
            int p2 = kk*4 + j;
            uint2 w = WB[p2*32 + c];
            float4 h4 = *(const float4*)(&sh3[m][p2*4]);
            q0 = fmaf(h4.x, bflo(w.x), q0);
            q1 = fmaf(h4.y, bfhi(w.x), q1);
            q2 = fmaf(h4.z, bflo(w.y), q2);
            q3 = fmaf(h4.w, bfhi(w.y), q3);
        }
        float yb = (q0+q1) + (q2+q3);
        yb += __shfl_xor(yb, 32);
        yb += vA[96+c];
        yb = gelu(yb);
        float sb2 = yb;
        #pragma unroll
        for (int o = 16; o > 0; o >>= 1) sb2 += __shfl_xor(sb2, o);
        float mb = sb2 * (1.0f/H2);
        float db = yb - mb;
        float vb = db*db;
        #pragma unroll
        for (int o = 16; o > 0; o >>= 1) vb += __shfl_xor(vb, o);
        hv += db * rsqrtf(vb*(1.0f/H2) + 1e-5f) * vA[128+c] + vA[160+c];
    }

    // ---- out-proj + softmax + p_win (wave per row, wave-local) ----
    sh2[m][c] = gelu(hv);
    int orow = perm[t*MT + m];
    if (orow < 0) return;
    const float* W = Ow + (size_t)e*32*NOUT;
    float acc = (lane < NOUT) ? Ob[e*NOUT + lane] : -INFINITY;
    #pragma unroll
    for (int k = 0; k < 32; k++){
        float gk = sh2[m][k];
        if (lane < NOUT) acc = fmaf(gk, W[k*NOUT + lane], acc);
    }
    if (lane < NOUT) out[(size_t)orow*NOUT + lane] = acc;
    float mx = acc;
    #pragma unroll
    for (int o = 32; o > 0; o >>= 1) mx = fmaxf(mx, __shfl_xor(mx, o));
    float pp = (lane < NOUT) ? expf(acc - mx) : 0.0f;
    float sum = pp;
    #pragma unroll
    for (int o = 32; o > 0; o >>= 1) sum += __shfl_xor(sum, o);
    float pb = (lane < NOUT) ? pp * bins[lane] : 0.0f;
    float sb = pb;
    #pragma unroll
    for (int o = 32; o > 0; o >>= 1) sb += __shfl_xor(sb, o);
    if (lane == 0) out[(size_t)N*NOUT + orow] = sb / sum;
}

extern "C" void kernel_launch(void* const* d_in, const int* in_sizes, int n_in,
                              void* d_out, int out_size, void* d_ws, size_t ws_size,
                              hipStream_t stream){
    const int*   piece_idx = (const int*)d_in[0];
    const int*   side_flag = (const int*)d_in[1];
    const int*   ep_file   = (const int*)d_in[2];
    const float* castle_ms = (const float*)d_in[3];
    const float* fifty_a   = (const float*)d_in[4];
    const int*   desc      = (const int*)d_in[5];
    const float* Wp_w  = (const float*)d_in[6];
    const float* Wp_b  = (const float*)d_in[7];
    const float* Wc_w  = (const float*)d_in[8];
    const float* Wc_b  = (const float*)d_in[9];
    const float* Wep_w = (const float*)d_in[10];
    const float* Wep_b = (const float*)d_in[11];
    const float* Wf_w  = (const float*)d_in[12];
    const float* Wf_b  = (const float*)d_in[13];
    const float* fc1_w = (const float*)d_in[14];
    const float* fc1_b = (const float*)d_in[15];
    const float* ln1_g = (const float*)d_in[16];
    const float* ln1_b = (const float*)d_in[17];
    const float* fc2_w = (const float*)d_in[18];
    const float* fc2_b = (const float*)d_in[19];
    const float* ln2_g = (const float*)d_in[20];
    const float* ln2_b = (const float*)d_in[21];
    const float* blkA_w  = (const float*)d_in[22];
    const float* blkA_b  = (const float*)d_in[23];
    const float* blkA_g  = (const float*)d_in[24];
    const float* blkA_be = (const float*)d_in[25];
    const float* blkB_w  = (const float*)d_in[26];
    const float* blkB_b  = (const float*)d_in[27];
    const float* blkB_g  = (const float*)d_in[28];
    const float* blkB_be = (const float*)d_in[29];
    const float* out_w = (const float*)d_in[30];
    const float* out_b = (const float*)d_in[31];
    const float* bins  = (const float*)d_in[32];

    char* wsp = (char*)d_ws;
    auto alloc = [&](size_t bytes){ void* p = (void*)wsp; wsp += (bytes + 255) & ~(size_t)255; return p; };
    int*            perm    = (int*)            alloc((size_t)NPAD*4);
    int*            tile_e  = (int*)            alloc((size_t)NTILE*4);
    int4*           garr    = (int4*)           alloc((size_t)GMAX*16);
    int*            ngroups = (int*)            alloc(256);
    unsigned short* Wt      = (unsigned short*) alloc((size_t)E*H1*D_IN*2);
    unsigned short* xs      = (unsigned short*) alloc((size_t)(NPAD+128)*D_IN*2);
    float*          h1p     = (float*)          alloc((size_t)KSPLIT*NROWS*H1*4);

    k_sort<<<1, 256, 0, stream>>>(desc, perm, tile_e, garr, ngroups);
    k_prep<<<NPAD + NCONVBLK, 256, 0, stream>>>(perm, piece_idx, side_flag, ep_file,
                                                castle_ms, fifty_a, desc,
                                                Wp_w, Wp_b, Wc_w, Wc_b,
                                                Wep_w, Wep_b, Wf_w, Wf_b,
                                                xs, fc1_w, Wt);
    k_fc1<<<dim3(GMAX, KSPLIT, 2), 256, 0, stream>>>(garr, ngroups, xs, Wt, h1p);
    k_tail<<<NTILE, 1024, 0, stream>>>(tile_e, perm, h1p, fc1_b, ln1_g, ln1_b,
                                       fc2_w, fc2_b, ln2_g, ln2_b,
                                       blkA_w, blkA_b, blkA_g, blkA_be,
                                       blkB_w, blkB_b, blkB_g, blkB_be,
                                       out_w, out_b, bins, (float*)d_out);
}

// Round 9
// 310.333 us; speedup vs baseline: 1.0971x; 1.0971x over previous
//
#include <hip/hip_runtime.h>
#include <math.h>

#define N 4096
#define E 32
#define NBLK 12
#define D_IN 2240
#define H1 256
#define H2 32
#define NOUT 51
#define MT 16
#define NPAD (N + E*(MT-1))   // 4576
#define NTILE (NPAD/MT)       // 286
#define KSPLIT 4
#define NROWS 4608
#define GMAX 96
#define NCONVBLK (35*4*E)     // 4480

typedef short s8v __attribute__((ext_vector_type(8)));
typedef float f4v __attribute__((ext_vector_type(4)));

__device__ __forceinline__ float gelu(float x){
    return 0.5f * x * (1.0f + erff(x * 0.70710678118654752f));
}
__device__ __forceinline__ unsigned short f2bf(float f){
    unsigned int u = __float_as_uint(f);
    unsigned int r = (u + 0x7fffu + ((u >> 16) & 1u)) >> 16;
    return (unsigned short)r;
}
__device__ __forceinline__ float bflo(unsigned int u){ return __uint_as_float(u << 16); }
__device__ __forceinline__ float bfhi(unsigned int u){ return __uint_as_float(u & 0xffff0000u); }

// --- DPP rotation-butterfly reduction over each 32-lane half (sum) ---
template<int CTRL>
__device__ __forceinline__ float dppadd(float x){
    int y = __builtin_amdgcn_update_dpp(0, __float_as_int(x), CTRL, 0xF, 0xF, true);
    return x + __int_as_float(y);
}
__device__ __forceinline__ float red32(float x){
    x = dppadd<0x121>(x);   // row_ror:1
    x = dppadd<0x122>(x);   // row_ror:2
    x = dppadd<0x124>(x);   // row_ror:4
    x = dppadd<0x128>(x);   // row_ror:8  -> each 16-group holds its sum
    int y = __builtin_amdgcn_ds_swizzle(__float_as_int(x), 0x401F);  // xor16
    return x + __int_as_float(y);
}

// ---------------- sort rows by expert + build 8-tile groups ----------------
__global__ void k_sort(const int* __restrict__ desc,
                       int* __restrict__ perm, int* __restrict__ tile_e,
                       int4* __restrict__ garr, int* __restrict__ ngroups){
    __shared__ int scnt[E];
    __shared__ int spoff[E+1];
    __shared__ int scur[E];
    int tid = threadIdx.x;
    if (tid < E) scnt[tid] = 0;
    __syncthreads();
    for (int n = tid; n < N; n += blockDim.x) atomicAdd(&scnt[desc[n]], 1);
    __syncthreads();
    if (tid == 0){
        int run = 0;
        for (int e = 0; e < E; e++){ spoff[e] = run; run += ((scnt[e] + MT - 1)/MT)*MT; }
        spoff[E] = run;
        int ng = 0;
        for (int e = 0; e < E; e++){
            int t0 = spoff[e]/MT, t1 = spoff[e+1]/MT;
            for (int t = t0; t < t1; t += 8){
                int nv = t1 - t; if (nv > 8) nv = 8;
                if (ng < GMAX) garr[ng] = make_int4(t, e, nv, 0);
                ng++;
            }
        }
        *ngroups = (ng > GMAX) ? GMAX : ng;
    }
    __syncthreads();
    if (tid < E) scur[tid] = spoff[tid];
    for (int p = tid; p < NPAD; p += blockDim.x) perm[p] = -1;
    __syncthreads();
    for (int n = tid; n < N; n += blockDim.x){
        int p = atomicAdd(&scur[desc[n]], 1);
        perm[p] = n;
    }
    for (int t = tid; t < NTILE; t += blockDim.x){
        int p0 = t*MT;
        int e = -1;
        if (p0 < spoff[E]){
            for (int q = 0; q < E; q++){
                if (p0 >= spoff[q] && p0 < spoff[q+1]){ e = q; break; }
            }
        }
        tile_e[t] = e;
    }
}

// -------- merged: build feature vectors (blocks 0..NPAD-1) + convert fc1_w (rest) --------
__global__ void k_prep(const int* __restrict__ perm,
                       const int* __restrict__ piece_idx,
                       const int* __restrict__ side_flag,
                       const int* __restrict__ ep_file,
                       const float* __restrict__ castle_ms,
                       const float* __restrict__ fifty_a,
                       const int* __restrict__ desc_idx,
                       const float* __restrict__ Wp_w, const float* __restrict__ Wp_b,
                       const float* __restrict__ Wc_w, const float* __restrict__ Wc_b,
                       const float* __restrict__ Wep_w, const float* __restrict__ Wep_b,
                       const float* __restrict__ Wf_w, const float* __restrict__ Wf_b,
                       unsigned short* __restrict__ xs,
                       const float* __restrict__ W1, unsigned short* __restrict__ Wt){
    __shared__ float lds[64][65];
    int tid = threadIdx.x;
    if (blockIdx.x >= NPAD){
        int b = blockIdx.x - NPAD;
        int kt = b % 35;
        int nt = (b / 35) & 3;
        int e  = b / 140;
        int k0 = kt*64, n0 = nt*64;
        int kk = tid >> 4, nn = (tid & 15) * 4;
        const float* src = W1 + ((size_t)e*D_IN + k0)*H1 + n0;
        #pragma unroll
        for (int r = 0; r < 4; r++){
            float4 v = *(const float4*)(src + (size_t)(kk + r*16)*H1 + nn);
            lds[kk + r*16][nn]   = v.x;
            lds[kk + r*16][nn+1] = v.y;
            lds[kk + r*16][nn+2] = v.z;
            lds[kk + r*16][nn+3] = v.w;
        }
        __syncthreads();
        int n = tid >> 2, kq = tid & 3;
        s8v p0, p1;
        #pragma unroll
        for (int j = 0; j < 8; j++) p0[j] = (short)f2bf(lds[kq*16 + j][n]);
        #pragma unroll
        for (int j = 0; j < 8; j++) p1[j] = (short)f2bf(lds[kq*16 + 8 + j][n]);
        unsigned short* dst = Wt + ((size_t)(e*H1 + n0 + n))*D_IN + k0 + kq*16;
        *(s8v*)dst       = p0;
        *(s8v*)(dst + 8) = p1;
        return;
    }
    int pos = blockIdx.x;
    int row = perm[pos];
    unsigned short* xr = xs + (size_t)pos * D_IN;
    if (row < 0){
        s8v z = {0,0,0,0,0,0,0,0};
        for (int t = tid; t < D_IN/8; t += blockDim.x) *(s8v*)(xr + t*8) = z;
        return;
    }
    int d = desc_idx[row];
    int s = side_flag[row];
    __shared__ int pidx[64];
    if (tid < 64) pidx[tid] = piece_idx[row*64 + tid];
    __syncthreads();
    const float* Wp  = s ? Wp_b  : Wp_w;
    const float* Wc  = s ? Wc_b  : Wc_w;
    const float* Wep = s ? Wep_b : Wep_w;
    const float* Wf  = s ? Wf_b  : Wf_w;
    int ep  = ep_file[row];
    int epc = ep > 0 ? ep : 0;
    float a = fifty_a[row];
    for (int t = tid; t < D_IN/8; t += blockDim.x){
        int i0 = t*8;
        float v[8];
        if (i0 < 2048){
            int sq = i0 >> 5, c0 = i0 & 31;
            int pc = pidx[sq];
            float msk = pc >= 0 ? 1.0f : 0.0f;
            int pcc = pc > 0 ? pc : 0;
            const float* base = Wp + (((size_t)d*64 + sq)*12 + pcc)*32 + c0;
            float4 a0 = *(const float4*)base;
            float4 a1 = *(const float4*)(base + 4);
            v[0]=a0.x*msk; v[1]=a0.y*msk; v[2]=a0.z*msk; v[3]=a0.w*msk;
            v[4]=a1.x*msk; v[5]=a1.y*msk; v[6]=a1.z*msk; v[7]=a1.w*msk;
        } else if (i0 < 2176){
            int j = i0 - 2048; int ci = j >> 5, c0 = j & 31;
            float cv = castle_ms[row*4 + ci];
            const float* base = Wc + ((size_t)d*4 + ci)*32 + c0;
            float4 a0 = *(const float4*)base;
            float4 a1 = *(const float4*)(base + 4);
            v[0]=a0.x*cv; v[1]=a0.y*cv; v[2]=a0.z*cv; v[3]=a0.w*cv;
            v[4]=a1.x*cv; v[5]=a1.y*cv; v[6]=a1.z*cv; v[7]=a1.w*cv;
        } else if (i0 < 2208){
            int c0 = i0 - 2176;
            float msk = ep >= 0 ? 1.0f : 0.0f;
            const float* base = Wep + ((size_t)d*8 + epc)*32 + c0;
            float4 a0 = *(const float4*)base;
            float4 a1 = *(const float4*)(base + 4);
            v[0]=a0.x*msk; v[1]=a0.y*msk; v[2]=a0.z*msk; v[3]=a0.w*msk;
            v[4]=a1.x*msk; v[5]=a1.y*msk; v[6]=a1.z*msk; v[7]=a1.w*msk;
        } else {
            int c0 = i0 - 2208;
            #pragma unroll
            for (int j = 0; j < 8; j++)
                v[j] = (1.0f - a) * Wf[(size_t)d*64 + c0 + j] + a * Wf[(size_t)d*64 + 32 + c0 + j];
        }
        s8v p;
        #pragma unroll
        for (int j = 0; j < 8; j++) p[j] = (short)f2bf(v[j]);
        *(s8v*)(xr + i0) = p;
    }
}

// ------- fc1 MFMA: groups of 128 rows x 256 cols, K split 4, partial f32 out -------
__launch_bounds__(256)
__global__ void k_fc1(const int4* __restrict__ garr, const int* __restrict__ ngroups,
                      const unsigned short* __restrict__ xs,
                      const unsigned short* __restrict__ Wt,
                      float* __restrict__ h1p){
    int g = blockIdx.x;
    if (g >= *ngroups) return;
    int4 gi = garr[g];
    int tile0 = gi.x, e = gi.y, nv = gi.z;
    int kc = blockIdx.y, nh = blockIdx.z;
    int kstart = (kc <= 2) ? kc*18 : 53;
    int nsteps = (kc < 2) ? 18 : 17;
    int lane = threadIdx.x & 63, wave = threadIdx.x >> 6;
    int quad = lane >> 4, l16 = lane & 15;
    int col0 = nh*128 + wave*32 + l16;
    const unsigned short* Ab = xs + (size_t)(tile0*MT + l16)*D_IN + quad*8;
    const unsigned short* B0 = Wt + ((size_t)e*H1 + col0)*D_IN + quad*8;
    const unsigned short* B1 = B0 + (size_t)16*D_IN;
    f4v acc[8][2];
    #pragma unroll
    for (int mt = 0; mt < 8; mt++){ acc[mt][0] = (f4v){0.f,0.f,0.f,0.f}; acc[mt][1] = (f4v){0.f,0.f,0.f,0.f}; }
    int kend = kstart + nsteps;
    #pragma unroll 2
    for (int s = kstart; s < kend; s++){
        int ko = s*32;
        s8v b0 = *(const s8v*)(B0 + ko);
        s8v b1 = *(const s8v*)(B1 + ko);
        #pragma unroll
        for (int mt = 0; mt < 8; mt++){
            s8v av = *(const s8v*)(Ab + (size_t)mt*MT*D_IN + ko);
            acc[mt][0] = __builtin_amdgcn_mfma_f32_16x16x32_bf16(av, b0, acc[mt][0], 0, 0, 0);
            acc[mt][1] = __builtin_amdgcn_mfma_f32_16x16x32_bf16(av, b1, acc[mt][1], 0, 0, 0);
        }
    }
    float* out = h1p + (size_t)kc*NROWS*H1;
    #pragma unroll
    for (int mt = 0; mt < 8; mt++){
        if (mt >= nv) break;
        int posb = (tile0 + mt)*MT + quad*4;
        #pragma unroll
        for (int r = 0; r < 4; r++){
            out[(size_t)(posb + r)*H1 + col0]      = acc[mt][0][r];
            out[(size_t)(posb + r)*H1 + col0 + 16] = acc[mt][1][r];
        }
    }
}

// ------- fused tail (round-6 structure + DPP one-pass LN + register weight prefetch) -------
__launch_bounds__(512)
__global__ void k_tail(const int* __restrict__ tile_e, const int* __restrict__ perm,
                       const float* __restrict__ h1p, const float* __restrict__ b1,
                       const float* __restrict__ g1, const float* __restrict__ be1,
                       const float* __restrict__ W2, const float* __restrict__ b2,
                       const float* __restrict__ g2, const float* __restrict__ be2,
                       const float* __restrict__ Aw, const float* __restrict__ Abv,
                       const float* __restrict__ Ag, const float* __restrict__ Abe,
                       const float* __restrict__ Bw, const float* __restrict__ Bb,
                       const float* __restrict__ Bg, const float* __restrict__ Bbe,
                       const float* __restrict__ Ow, const float* __restrict__ Ob,
                       const float* __restrict__ bins,
                       float* __restrict__ out){
    int t = blockIdx.x;
    int e = tile_e[t];
    if (e < 0) return;
    int tid = threadIdx.x;

    __shared__ __align__(16) unsigned int smem[12288];   // 48 KB union
    __shared__ __align__(16) float vecs[NBLK*6*32];      // 9 KB
    __shared__ __align__(16) float sh2[MT][36];
    __shared__ __align__(16) float sh3[MT][36];

    float* shf = (float*)smem;                 // [16][260] floats, phase 1
    unsigned int* W2pk = smem + 4160;          // 4096 u32, phase 1

    // ---- prefetch residual weights into registers (overlaps phase 1) ----
    unsigned int wreg[24];
    {
        int h = tid & 1, q = tid >> 1, cc = q & 31, p2 = q >> 5;
        int k0 = 4*p2 + 2*h;
        #pragma unroll
        for (int i = 0; i < 24; i++){
            const float* src = (i & 1) ? Bw : Aw;
            size_t base = ((size_t)(i >> 1)*E + e)*1024;
            unsigned int lo = f2bf(src[base + k0*32 + cc]);
            unsigned int hi = f2bf(src[base + (k0+1)*32 + cc]);
            wreg[i] = lo | (hi << 16);
        }
    }
    // ---- phase 1a: W2 -> bf16 k-pair packed ----
    {
        const float* W2e = W2 + (size_t)e*H1*H2;
        for (int j = tid; j < 4096; j += 512){
            int h = j & 1, q = j >> 1, cc = q & 31, p2 = q >> 5;
            int k0 = 4*p2 + 2*h;
            unsigned int lo = f2bf(W2e[k0*32 + cc]);
            unsigned int hi = f2bf(W2e[(k0+1)*32 + cc]);
            W2pk[(p2*32 + cc)*2 + h] = lo | (hi << 16);
        }
    }
    // ---- phase 1b: LN/bias vectors for all 12 blocks ----
    for (int j = tid; j < NBLK*6*32; j += 512){
        int cc = j & 31, vi = (j >> 5) % 6, tb = j / 192;
        size_t wb = (size_t)tb*E + e;
        const float* src;
        switch(vi){ case 0: src=Abv; break; case 1: src=Ag; break; case 2: src=Abe; break;
                    case 3: src=Bb;  break; case 4: src=Bg; break; default: src=Bbe; }
        vecs[j] = src[wb*32 + cc];
    }
    // ---- phase 1c: sum fc1 K-partials + bias + gelu -> shf ----
    for (int slot = tid; slot < MT*64; slot += 512){
        int r = slot >> 6, c4 = (slot & 63) << 2;
        int row = t*MT + r;
        float4 v = {0.f,0.f,0.f,0.f};
        #pragma unroll
        for (int kc = 0; kc < KSPLIT; kc++){
            float4 p = *(const float4*)(h1p + ((size_t)kc*NROWS + row)*H1 + c4);
            v.x += p.x; v.y += p.y; v.z += p.z; v.w += p.w;
        }
        float4 bb = *(const float4*)(b1 + e*H1 + c4);
        shf[r*260 + c4]   = gelu(v.x + bb.x);
        shf[r*260 + c4+1] = gelu(v.y + bb.y);
        shf[r*260 + c4+2] = gelu(v.z + bb.z);
        shf[r*260 + c4+3] = gelu(v.w + bb.w);
    }
    __syncthreads();

    int m = tid >> 5, c = tid & 31;
    // ---- LN1 (one-pass: parallel sum / sumsq reductions) ----
    {
        float s = 0.f, s2 = 0.f;
        #pragma unroll
        for (int j = 0; j < 8; j++){
            float x = shf[m*260 + c + 32*j];
            s += x; s2 += x*x;
        }
        s  = red32(s);
        s2 = red32(s2);
        float mean = s * (1.0f/H1);
        float var  = s2 * (1.0f/H1) - mean*mean;
        float rs = rsqrtf(var + 1e-5f);
        #pragma unroll
        for (int j = 0; j < 8; j++){
            int k = c + 32*j;
            shf[m*260 + k] = (shf[m*260 + k] - mean) * rs * g1[e*H1 + k] + be1[e*H1 + k];
        }
    }
    // ---- fc2 GEMV [256->32] + gelu + LN2 (one-pass) ----
    float hv;
    {
        const uint2* W2p = (const uint2*)W2pk;
        float q0=0.f,q1=0.f,q2=0.f,q3=0.f;
        #pragma unroll 8
        for (int p2 = 0; p2 < 64; p2++){
            uint2 w = W2p[p2*32 + c];
            float4 h4 = *(const float4*)(shf + m*260 + p2*4);
            q0 = fmaf(h4.x, bflo(w.x), q0);
            q1 = fmaf(h4.y, bfhi(w.x), q1);
            q2 = fmaf(h4.z, bflo(w.y), q2);
            q3 = fmaf(h4.w, bfhi(w.y), q3);
        }
        float acc = (q0+q1) + (q2+q3) + b2[e*H2 + c];
        float y = gelu(acc);
        float s  = red32(y);
        float s2 = red32(y*y);
        float mean2 = s * (1.0f/H2);
        float var2  = s2 * (1.0f/H2) - mean2*mean2;
        hv = (y - mean2) * rsqrtf(var2 + 1e-5f) * g2[e*H2+c] + be2[e*H2+c];
    }
    __syncthreads();   // done with shf/W2pk

    // ---- phase 2: dump prefetched residual weights to LDS ----
    #pragma unroll
    for (int i = 0; i < 24; i++) smem[i*512 + tid] = wreg[i];
    __syncthreads();

    // ---- 12 residual blocks: zero barriers, one-pass LN ----
    for (int tb = 0; tb < NBLK; tb++){
        const float* vA = &vecs[tb*192];
        const uint2* WA = (const uint2*)(smem + (tb*2+0)*512);
        const uint2* WB = (const uint2*)(smem + (tb*2+1)*512);
        sh2[m][c] = hv;
        float q0=0.f,q1=0.f,q2=0.f,q3=0.f;
        #pragma unroll
        for (int p2 = 0; p2 < 8; p2++){
            uint2 w = WA[p2*32 + c];
            float4 h4 = *(const float4*)(&sh2[m][p2*4]);
            q0 = fmaf(h4.x, bflo(w.x), q0);
            q1 = fmaf(h4.y, bfhi(w.x), q1);
            q2 = fmaf(h4.z, bflo(w.y), q2);
            q3 = fmaf(h4.w, bfhi(w.y), q3);
        }
        float ya = (q0+q1) + (q2+q3) + vA[c];
        ya = gelu(ya);
        float sa  = red32(ya);
        float sa2 = red32(ya*ya);
        float ma = sa * (1.0f/H2);
        float va = sa2 * (1.0f/H2) - ma*ma;
        float yA = (ya - ma) * rsqrtf(va + 1e-5f) * vA[32+c] + vA[64+c];
        sh3[m][c] = yA;
        q0=0.f; q1=0.f; q2=0.f; q3=0.f;
        #pragma unroll
        for (int p2 = 0; p2 < 8; p2++){
            uint2 w = WB[p2*32 + c];
            float4 h4 = *(const float4*)(&sh3[m][p2*4]);
            q0 = fmaf(h4.x, bflo(w.x), q0);
            q1 = fmaf(h4.y, bfhi(w.x), q1);
            q2 = fmaf(h4.z, bflo(w.y), q2);
            q3 = fmaf(h4.w, bfhi(w.y), q3);
        }
        float yb = (q0+q1) + (q2+q3) + vA[96+c];
        yb = gelu(yb);
        float sb  = red32(yb);
        float sb2 = red32(yb*yb);
        float mb = sb * (1.0f/H2);
        float vb = sb2 * (1.0f/H2) - mb*mb;
        hv += (yb - mb) * rsqrtf(vb + 1e-5f) * vA[128+c] + vA[160+c];
    }

    // ---- out-proj + softmax + p_win ----
    sh2[m][c] = gelu(hv);
    __syncthreads();
    int wave = tid >> 6, lane = tid & 63;
    const float* W = Ow + (size_t)e*32*NOUT;
    for (int rr = wave; rr < MT; rr += 8){
        int orow = perm[t*MT + rr];
        if (orow < 0) continue;
        float acc = (lane < NOUT) ? Ob[e*NOUT + lane] : -INFINITY;
        #pragma unroll
        for (int k = 0; k < 32; k++){
            float gk = sh2[rr][k];
            if (lane < NOUT) acc = fmaf(gk, W[k*NOUT + lane], acc);
        }
        if (lane < NOUT) out[(size_t)orow*NOUT + lane] = acc;
        float mx = acc;
        #pragma unroll
        for (int o = 32; o > 0; o >>= 1) mx = fmaxf(mx, __shfl_xor(mx, o));
        float pp = (lane < NOUT) ? expf(acc - mx) : 0.0f;
        float sum = pp;
        float pb = (lane < NOUT) ? pp * bins[lane] : 0.0f;
        float sb = pb;
        #pragma unroll
        for (int o = 32; o > 0; o >>= 1){ sum += __shfl_xor(sum, o); sb += __shfl_xor(sb, o); }
        if (lane == 0) out[(size_t)N*NOUT + orow] = sb / sum;
    }
}

extern "C" void kernel_launch(void* const* d_in, const int* in_sizes, int n_in,
                              void* d_out, int out_size, void* d_ws, size_t ws_size,
                              hipStream_t stream){
    const int*   piece_idx = (const int*)d_in[0];
    const int*   side_flag = (const int*)d_in[1];
    const int*   ep_file   = (const int*)d_in[2];
    const float* castle_ms = (const float*)d_in[3];
    const float* fifty_a   = (const float*)d_in[4];
    const int*   desc      = (const int*)d_in[5];
    const float* Wp_w  = (const float*)d_in[6];
    const float* Wp_b  = (const float*)d_in[7];
    const float* Wc_w  = (const float*)d_in[8];
    const float* Wc_b  = (const float*)d_in[9];
    const float* Wep_w = (const float*)d_in[10];
    const float* Wep_b = (const float*)d_in[11];
    const float* Wf_w  = (const float*)d_in[12];
    const float* Wf_b  = (const float*)d_in[13];
    const float* fc1_w = (const float*)d_in[14];
    const float* fc1_b = (const float*)d_in[15];
    const float* ln1_g = (const float*)d_in[16];
    const float* ln1_b = (const float*)d_in[17];
    const float* fc2_w = (const float*)d_in[18];
    const float* fc2_b = (const float*)d_in[19];
    const float* ln2_g = (const float*)d_in[20];
    const float* ln2_b = (const float*)d_in[21];
    const float* blkA_w  = (const float*)d_in[22];
    const float* blkA_b  = (const float*)d_in[23];
    const float* blkA_g  = (const float*)d_in[24];
    const float* blkA_be = (const float*)d_in[25];
    const float* blkB_w  = (const float*)d_in[26];
    const float* blkB_b  = (const float*)d_in[27];
    const float* blkB_g  = (const float*)d_in[28];
    const float* blkB_be = (const float*)d_in[29];
    const float* out_w = (const float*)d_in[30];
    const float* out_b = (const float*)d_in[31];
    const float* bins  = (const float*)d_in[32];

    char* wsp = (char*)d_ws;
    auto alloc = [&](size_t bytes){ void* p = (void*)wsp; wsp += (bytes + 255) & ~(size_t)255; return p; };
    int*            perm    = (int*)            alloc((size_t)NPAD*4);
    int*            tile_e  = (int*)            alloc((size_t)NTILE*4);
    int4*           garr    = (int4*)           alloc((size_t)GMAX*16);
    int*            ngroups = (int*)            alloc(256);
    unsigned short* Wt      = (unsigned short*) alloc((size_t)E*H1*D_IN*2);
    unsigned short* xs      = (unsigned short*) alloc((size_t)(NPAD+128)*D_IN*2);
    float*          h1p     = (float*)          alloc((size_t)KSPLIT*NROWS*H1*4);

    k_sort<<<1, 256, 0, stream>>>(desc, perm, tile_e, garr, ngroups);
    k_prep<<<NPAD + NCONVBLK, 256, 0, stream>>>(perm, piece_idx, side_flag, ep_file,
                                                castle_ms, fifty_a, desc,
                                                Wp_w, Wp_b, Wc_w, Wc_b,
                                                Wep_w, Wep_b, Wf_w, Wf_b,
                                                xs, fc1_w, Wt);
    k_fc1<<<dim3(GMAX, KSPLIT, 2), 256, 0, stream>>>(garr, ngroups, xs, Wt, h1p);
    k_tail<<<NTILE, 512, 0, stream>>>(tile_e, perm, h1p, fc1_b, ln1_g, ln1_b,
                                      fc2_w, fc2_b, ln2_g, ln2_b,
                                      blkA_w, blkA_b, blkA_g, blkA_be,
                                      blkB_w, blkB_b, blkB_g, blkB_be,
                                      out_w, out_b, bins, (float*)d_out);
}